// Round 4
// baseline (258.388 us; speedup 1.0000x reference)
//
#include <hip/hip_runtime.h>
#include <math.h>

#define Bn 4
#define Tn 2048
#define En 1024
#define Hn 16
#define Dn 64
#define RS2 (2 * En)
#define QSCALE 0.18033688f   // (1/sqrt(64)) * log2(e)  -> softmax in exp2 domain
#define SMAX 16.0f           // static softmax max (log2 domain); scores bounded << 16

typedef __attribute__((ext_vector_type(8))) short bfrag;   // 8 bf16 in 4 VGPRs
typedef __attribute__((ext_vector_type(4))) short sfrag4;  // 4 bf16 in 2 VGPRs
typedef __attribute__((ext_vector_type(4))) float ffrag;   // 4 fp32 acc

__device__ __forceinline__ unsigned short f2bf(float f) {
    union { float f; unsigned int u; } v; v.f = f;
    unsigned int r = v.u + 0x7fffu + ((v.u >> 16) & 1u);   // RNE
    return (unsigned short)(r >> 16);
}
__device__ __forceinline__ unsigned short f2bf_fast(float f) {  // positive, no NaN
    union { float f; unsigned int u; } v; v.f = f;
    return (unsigned short)((v.u + 0x8000u) >> 16);
}

__device__ __forceinline__ void glds16(const unsigned short* g, unsigned short* l) {
    __builtin_amdgcn_global_load_lds(
        (const __attribute__((address_space(1))) unsigned int*)g,
        (__attribute__((address_space(3))) unsigned int*)l, 16, 0, 0);
}

#define VMCNT(n) asm volatile("s_waitcnt vmcnt(" #n ")" ::: "memory")
#define LGKM0()  do { asm volatile("s_waitcnt lgkmcnt(0)" ::: "memory"); \
                      __builtin_amdgcn_sched_barrier(0); } while (0)
#define BAR()    __builtin_amdgcn_s_barrier()

// ---------------- fp32 -> bf16 elementwise ----------------
__global__ __launch_bounds__(256) void f2bf_vec(const float* __restrict__ in,
                                                unsigned short* __restrict__ out, int n) {
    int i = (blockIdx.x * 256 + threadIdx.x) * 4;
    if (i >= n) return;
    float4 v = *(const float4*)(in + i);
    ushort4 o;
    o.x = f2bf(v.x); o.y = f2bf(v.y); o.z = f2bf(v.z); o.w = f2bf(v.w);
    *(ushort4*)(out + i) = o;
}

// ---------------- W[K][N] fp32 -> Wt[N][K] bf16 ----------------
__global__ __launch_bounds__(256) void transpose_f2bf(const float* __restrict__ W,
                                                      unsigned short* __restrict__ Wt,
                                                      int K, int N) {
    __shared__ float s[64][65];
    const int kt = blockIdx.y * 64, nt = blockIdx.x * 64;
    const int tx = threadIdx.x & 15, ty = threadIdx.x >> 4;
#pragma unroll
    for (int i = 0; i < 4; ++i) {
        float4 v = *(const float4*)&W[(size_t)(kt + ty + i * 16) * N + nt + tx * 4];
        s[ty + i * 16][tx * 4 + 0] = v.x;
        s[ty + i * 16][tx * 4 + 1] = v.y;
        s[ty + i * 16][tx * 4 + 2] = v.z;
        s[ty + i * 16][tx * 4 + 3] = v.w;
    }
    __syncthreads();
#pragma unroll
    for (int i = 0; i < 4; ++i) {
        const int n = ty + i * 16;
        ushort4 o;
        o.x = f2bf(s[tx * 4 + 0][n]);
        o.y = f2bf(s[tx * 4 + 1][n]);
        o.z = f2bf(s[tx * 4 + 2][n]);
        o.w = f2bf(s[tx * 4 + 3][n]);
        *(ushort4*)&Wt[(size_t)(nt + n) * K + kt + tx * 4] = o;
    }
}

// ---------------- NT bf16 MFMA GEMM, 128x128, BK=64 (kept for proj) ----------------
template <int OUT_BF16, int VSPLIT>
__global__ __launch_bounds__(256) void gemm_nt_mfma(
    const unsigned short* __restrict__ A, const unsigned short* __restrict__ Bt,
    const float* __restrict__ bias, void* __restrict__ Cv, int ldc,
    unsigned short* __restrict__ vt, int vstart,
    int M, int N, int K, int qcols, int gx)
{
    __shared__ __attribute__((aligned(16))) unsigned short As[128 * 64];
    __shared__ __attribute__((aligned(16))) unsigned short Bs[128 * 64];

    const int t = threadIdx.x;
    const int w = t >> 6, l = t & 63;
    const int wmt = (w & 1) * 4, wnt = (w >> 1) * 4;
    const int nl = l & 15, lq = l >> 4;
    const int r8 = l >> 3, c8 = l & 7;
    const int cs8 = c8 ^ r8;

    const int flat = blockIdx.x;
    const int xcd = flat & 7;
    const int g = flat >> 3;
    const int bx = g % gx;
    const int by = xcd * 8 + g / gx;
    const int m0 = by * 128, n0 = bx * 128;

    ffrag acc[4][4];
#pragma unroll
    for (int i = 0; i < 4; ++i)
#pragma unroll
        for (int j = 0; j < 4; ++j)
#pragma unroll
            for (int r = 0; r < 4; ++r) acc[i][j][r] = 0.f;

    const unsigned short* Ag = A  + (size_t)(m0 + r8) * K + cs8 * 8;
    const unsigned short* Bg = Bt + (size_t)(n0 + r8) * K + cs8 * 8;

    const int iters = K >> 6;
#pragma unroll 1
    for (int it = 0; it < iters; ++it) {
        const int k0 = it << 6;
        __syncthreads();
#pragma unroll
        for (int r = 0; r < 4; ++r) {
            const int i = w * 4 + r;
            glds16(Ag + (size_t)(i * 8) * K + k0, &As[i * 512 + l * 8]);
            glds16(Bg + (size_t)(i * 8) * K + k0, &Bs[i * 512 + l * 8]);
        }
        __syncthreads();
#pragma unroll
        for (int ks = 0; ks < 2; ++ks) {
            bfrag af[4], bf[4];
#pragma unroll
            for (int i = 0; i < 4; ++i) {
                const int pos = ((ks * 4 + lq) ^ (nl & 7)) << 3;
                af[i] = *(const bfrag*)&As[((wmt + i) * 16 + nl) * 64 + pos];
                bf[i] = *(const bfrag*)&Bs[((wnt + i) * 16 + nl) * 64 + pos];
            }
#pragma unroll
            for (int i = 0; i < 4; ++i)
#pragma unroll
                for (int j = 0; j < 4; ++j)
                    acc[i][j] = __builtin_amdgcn_mfma_f32_16x16x32_bf16(af[i], bf[j], acc[i][j], 0, 0, 0);
        }
    }

    const int orow = lq * 4, ocol = nl;
#pragma unroll
    for (int i = 0; i < 4; ++i) {
        const int gm = m0 + (wmt + i) * 16 + orow;
#pragma unroll
        for (int j = 0; j < 4; ++j) {
            const int gn = n0 + (wnt + j) * 16 + ocol;
            const float bs = bias[gn];
            if (VSPLIT && gn >= vstart) {
                const int vc = gn - vstart;
                const int b  = gm / Tn;
                const int tt = gm - b * Tn;
                ushort4 o;
                o.x = f2bf(acc[i][j][0] + bs);
                o.y = f2bf(acc[i][j][1] + bs);
                o.z = f2bf(acc[i][j][2] + bs);
                o.w = f2bf(acc[i][j][3] + bs);
                *(ushort4*)&vt[(size_t)(b * Hn * Dn + vc) * Tn + tt] = o;
            } else {
                const float sc = (qcols && gn < qcols) ? QSCALE : 1.f;
#pragma unroll
                for (int r = 0; r < 4; ++r) {
                    const float vv = (acc[i][j][r] + bs) * sc;
                    if (OUT_BF16)
                        ((unsigned short*)Cv)[(size_t)(gm + r) * ldc + gn] = f2bf(vv);
                    else
                        ((float*)Cv)[(size_t)(gm + r) * ldc + gn] = vv;
                }
            }
        }
    }
}

// ---------------- QKV GEMM: 256x256 tile, BK=64, 8-wave, 4-phase counted-vmcnt ----------------
// A[8192][1024] bf16 @ Wqt[3072][1024]^T + b_qkv -> Q|K (qk, pre-scaled Q) and V^T (vt).
// 8 waves as WM=2 x WN=4, interleaved at 16-granularity; quadrant order per K-tile:
// (mh0,nh0),(mh0,nh1),(mh1,nh1),(mh1,nh0) so af is held ph1->ph2 and ph3->ph4, bf held
// ph2->ph3 (bf0 re-read at ph4 — cheaper than holding 16 more VGPRs live).
//
// REVISED stage/drain schedule (round-3 post-mortem: old plan had 1-phase vmcnt cover on
// b0' -> hard stall each K-tile; MfmaUtil 24%). New plan gives EVERY half-tile 3 phases
// of cover (~500+ cyc vs HBM ~300-900):
//   issue:  ph1: a0'+b0' (4 glds) | ph2: b1' (2) | ph3: a1' (2) | ph4: none
//   drain:  ph1: vmcnt(6) [drains b1, read ph2]   cover ph2(T-1)->ph1(T) = 3 phases
//           ph2: vmcnt(6) [drains a1, read ph3]   cover 3 phases
//           ph3: none
//           ph4: vmcnt(4) [drains a0',b0' for next ph1]  cover 3 phases
// Steady outstanding <= 8 glds; never drains to 0 mid-loop (T4). Tail: vmcnt 2/0/-/-.
// Prologue vmcnt(4) leaves {b1,a1}=4 in flight = steady-state ph1 precondition.
__global__ __launch_bounds__(512, 1) void gemm_qkv_256(
    const unsigned short* __restrict__ A,
    const unsigned short* __restrict__ Bt,
    const float* __restrict__ bias,
    unsigned short* __restrict__ qk,
    unsigned short* __restrict__ vt)
{
    __shared__ __attribute__((aligned(16))) unsigned short As[2][256 * 64];
    __shared__ __attribute__((aligned(16))) unsigned short Bs[2][256 * 64];

    const int t = threadIdx.x;
    const int w = t >> 6, l = t & 63;
    const int wm16 = (w & 1) << 4, wn16 = (w >> 1) << 4;
    const int nl = l & 15, lq = l >> 4, nl7 = l & 7;
    const int r8 = l >> 3, c8 = l & 7;
    const int cs8 = c8 ^ r8;

    // XCD-aware mapping: 384 blocks, 48 per XCD = 4 tile-rows x 12 tile-cols
    const int flat = blockIdx.x;
    const int g = flat >> 3;
    const int bx = g % 12;
    const int by = (flat & 7) * 4 + g / 12;
    const int m0 = by << 8, n0 = bx << 8;

    ffrag acc[8][4];
#pragma unroll
    for (int i = 0; i < 8; ++i)
#pragma unroll
        for (int j = 0; j < 4; ++j)
#pragma unroll
            for (int r = 0; r < 4; ++r) acc[i][j][r] = 0.f;

    const unsigned short* Ag = A  + (size_t)(m0 + r8) * 1024 + cs8 * 8;
    const unsigned short* Bg = Bt + (size_t)(n0 + r8) * 1024 + cs8 * 8;

#define STAGE_A(goff, kofs, dst)                                                      \
    _Pragma("unroll")                                                                 \
    for (int s = 0; s < 2; ++s) {                                                     \
        const int gg = (goff) + w * 2 + s;                                            \
        glds16(Ag + (size_t)(gg * 8) * 1024 + (kofs), (dst) + gg * 512 + l * 8);      \
    }
#define STAGE_B(goff, kofs, dst)                                                      \
    _Pragma("unroll")                                                                 \
    for (int s = 0; s < 2; ++s) {                                                     \
        const int gg = (goff) + w * 2 + s;                                            \
        glds16(Bg + (size_t)(gg * 8) * 1024 + (kofs), (dst) + gg * 512 + l * 8);      \
    }
#define LOAD_A(MH)                                                                    \
    _Pragma("unroll")                                                                 \
    for (int ks = 0; ks < 2; ++ks)                                                    \
        _Pragma("unroll")                                                             \
        for (int i = 0; i < 4; ++i)                                                   \
            af[ks][i] = *(const bfrag*)&Asc[(((MH) * 4 + i) * 32 + wm16 + nl) * 64 +  \
                                            (((ks * 4 + lq) ^ nl7) << 3)];
#define LOAD_B(NH)                                                                    \
    _Pragma("unroll")                                                                 \
    for (int ks = 0; ks < 2; ++ks)                                                    \
        _Pragma("unroll")                                                             \
        for (int j = 0; j < 2; ++j)                                                   \
            bf[ks][j] = *(const bfrag*)&Bsc[(((NH) * 2 + j) * 64 + wn16 + nl) * 64 +  \
                                            (((ks * 4 + lq) ^ nl7) << 3)];
#define MFMA_Q(MH, NH)                                                                \
    __builtin_amdgcn_s_setprio(1);                                                    \
    _Pragma("unroll")                                                                 \
    for (int ks = 0; ks < 2; ++ks)                                                    \
        _Pragma("unroll")                                                             \
        for (int i = 0; i < 4; ++i)                                                   \
            _Pragma("unroll")                                                         \
            for (int j = 0; j < 2; ++j)                                               \
                acc[(MH) * 4 + i][(NH) * 2 + j] = __builtin_amdgcn_mfma_f32_16x16x32_bf16( \
                    af[ks][i], bf[ks][j], acc[(MH) * 4 + i][(NH) * 2 + j], 0, 0, 0);  \
    __builtin_amdgcn_s_setprio(0);

    // prologue: tile 0 -> buf 0, stage order a0, b0, b1, a1; drain a0,b0 only
    STAGE_A(0, 0, &As[0][0]);
    STAGE_B(0, 0, &Bs[0][0]);
    STAGE_B(16, 0, &Bs[0][0]);
    STAGE_A(16, 0, &As[0][0]);
    VMCNT(4);            // a0,b0 landed; {b1,a1} = 4 glds in flight
    BAR();

#pragma unroll 1
    for (int it = 0; it < 16; ++it) {
        const int buf = it & 1;
        const size_t kn = (size_t)(it + 1) << 6;
        const bool more = it < 15;
        const unsigned short* Asc = &As[buf][0];
        const unsigned short* Bsc = &Bs[buf][0];
        unsigned short* Asn = &As[buf ^ 1][0];
        unsigned short* Bsn = &Bs[buf ^ 1][0];
        bfrag af[2][4], bf[2][2];

        // ---- ph1: quadrant (mh0, nh0); stage a0'+b0'; drain b1 (read ph2) ----
        LOAD_A(0);
        LOAD_B(0);
        if (more) { STAGE_A(0, kn, Asn); STAGE_B(0, kn, Bsn); VMCNT(6); } else { VMCNT(2); }
        BAR(); LGKM0();
        MFMA_Q(0, 0);
        BAR();

        // ---- ph2: quadrant (mh0, nh1); stage b1'; drain a1 (read ph3) ----
        LOAD_B(1);
        if (more) { STAGE_B(16, kn, Bsn); VMCNT(6); } else { VMCNT(0); }
        BAR(); LGKM0();
        MFMA_Q(0, 1);
        BAR();

        // ---- ph3: quadrant (mh1, nh1); stage a1'; no drain ----
        LOAD_A(1);
        if (more) { STAGE_A(16, kn, Asn); }
        BAR(); LGKM0();
        MFMA_Q(1, 1);
        BAR();

        // ---- ph4: quadrant (mh1, nh0); no stage; drain a0',b0' (read next ph1) ----
        LOAD_B(0);
        if (more) { VMCNT(4); }
        BAR(); LGKM0();
        MFMA_Q(1, 0);
        BAR();
    }

#undef STAGE_A
#undef STAGE_B
#undef LOAD_A
#undef LOAD_B
#undef MFMA_Q

    // epilogue: Q|K columns -> qk (Q pre-scaled), V columns -> vt transposed
    const int orow = lq * 4;
#pragma unroll
    for (int i = 0; i < 8; ++i) {
        const int gm = m0 + i * 32 + wm16 + orow;
#pragma unroll
        for (int j = 0; j < 4; ++j) {
            const int gn = n0 + j * 64 + wn16 + nl;
            const float bs = bias[gn];
            if (gn >= 2 * En) {
                const int vc = gn - 2 * En;
                const int b  = gm >> 11;
                const int tt = gm & (Tn - 1);
                ushort4 o;
                o.x = f2bf(acc[i][j][0] + bs);
                o.y = f2bf(acc[i][j][1] + bs);
                o.z = f2bf(acc[i][j][2] + bs);
                o.w = f2bf(acc[i][j][3] + bs);
                *(ushort4*)&vt[(size_t)(b * Hn * Dn + vc) * Tn + tt] = o;
            } else {
                const float sc = (gn < En) ? QSCALE : 1.f;
#pragma unroll
                for (int r = 0; r < 4; ++r)
                    qk[(size_t)(gm + r) * RS2 + gn] = f2bf((acc[i][j][r] + bs) * sc);
            }
        }
    }
}

// ---------------- MFMA flash attention, swapped-QK^T in-register softmax ----------------
__global__ __launch_bounds__(256, 4) void attn_mfma(
    const unsigned short* __restrict__ qkv,   // [B*T][2E]  Q|K, Q pre-scaled
    const unsigned short* __restrict__ vtg,   // [B*H*D][T] V transposed
    unsigned short* __restrict__ yattn)       // [B*T][E]
{
    __shared__ __attribute__((aligned(16))) unsigned short KT[128 * 64];
    __shared__ __attribute__((aligned(16))) unsigned short VT[64 * 128];

    const int t = threadIdx.x;
    const int w = t >> 6, l = t & 63;
    const int nl = l & 15, lq = l >> 4;
    const int flat = blockIdx.x;
    const int bh = flat & 63;
    const int qp = flat >> 6;         // 0..15
    const int b = bh >> 4, h = bh & 15;

    const unsigned short* qbase = qkv + (size_t)(b * Tn) * RS2 + h * Dn;
    const unsigned short* kbase = qbase + En;
    const unsigned short* vbase = vtg + (size_t)(bh * Dn) * Tn;
    unsigned short* yb = yattn + (size_t)(b * Tn) * En + h * Dn;

#pragma unroll 1
    for (int phase = 0; phase < 2; ++phase) {
        const int qt = phase ? (31 - qp) : qp;
        const int rowb = qt * 64 + w * 16;
        const int jmax = qt >> 1;
        const int qrow = rowb + nl;

        bfrag qf[2];
#pragma unroll
        for (int ks = 0; ks < 2; ++ks)
            qf[ks] = *(const bfrag*)(qbase + (size_t)(rowb + nl) * RS2 + ks * 32 + lq * 8);

        ffrag Oa[4];
        float li = 0.f;
#pragma unroll
        for (int dt = 0; dt < 4; ++dt)
#pragma unroll
            for (int r = 0; r < 4; ++r) Oa[dt][r] = 0.f;

        for (int j = 0; j <= jmax; ++j) {
            const int k0 = j << 7;
            __syncthreads();   // prior tile's frag reads done before restage
#pragma unroll
            for (int r = 0; r < 4; ++r) {
                const int i = w * 4 + r;
                glds16(kbase + (size_t)(k0 + i * 8 + (l >> 3)) * RS2 + (((l & 7) ^ (l >> 3)) << 3),
                       &KT[i * 512 + l * 8]);
            }
#pragma unroll
            for (int r = 0; r < 4; ++r) {
                const int i = w * 4 + r;
                const int key = ((i & 3) << 2) + (l >> 4);
                glds16(vbase + (size_t)(i * 4 + (l >> 4)) * Tn + k0 + (((l & 15) ^ key) << 3),
                       &VT[i * 512 + l * 8]);
            }
            __syncthreads();

            // QK^T swapped + softmax fully in-register
            bfrag pf[4];
#pragma unroll
            for (int cs = 0; cs < 4; ++cs) {
                const int n0 = cs * 2, n1 = cs * 2 + 1;
                const int pos0 = (lq ^ (nl & 7)) << 3;
                const int pos1 = ((4 + lq) ^ (nl & 7)) << 3;
                bfrag ka0 = *(const bfrag*)&KT[(n0 * 16 + nl) * 64 + pos0];
                bfrag kb0 = *(const bfrag*)&KT[(n0 * 16 + nl) * 64 + pos1];
                bfrag ka1 = *(const bfrag*)&KT[(n1 * 16 + nl) * 64 + pos0];
                bfrag kb1 = *(const bfrag*)&KT[(n1 * 16 + nl) * 64 + pos1];
                ffrag z0, z1;
#pragma unroll
                for (int r = 0; r < 4; ++r) { z0[r] = -SMAX; z1[r] = -SMAX; }
                __builtin_amdgcn_s_setprio(1);
                z0 = __builtin_amdgcn_mfma_f32_16x16x32_bf16(ka0, qf[0], z0, 0, 0, 0);
                z0 = __builtin_amdgcn_mfma_f32_16x16x32_bf16(kb0, qf[1], z0, 0, 0, 0);
                z1 = __builtin_amdgcn_mfma_f32_16x16x32_bf16(ka1, qf[0], z1, 0, 0, 0);
                z1 = __builtin_amdgcn_mfma_f32_16x16x32_bf16(kb1, qf[1], z1, 0, 0, 0);
                __builtin_amdgcn_s_setprio(0);
                if (j == jmax) {   // tile containing the diagonal: causal mask
#pragma unroll
                    for (int r = 0; r < 4; ++r) {
                        if (k0 + n0 * 16 + lq * 4 + r > qrow) z0[r] = -INFINITY;
                        if (k0 + n1 * 16 + lq * 4 + r > qrow) z1[r] = -INFINITY;
                    }
                }
#pragma unroll
                for (int r = 0; r < 4; ++r) {
                    const float p0 = __builtin_amdgcn_exp2f(z0[r]);
                    const float p1 = __builtin_amdgcn_exp2f(z1[r]);
                    li += p0;
                    li += p1;
                    pf[cs][r]     = (short)f2bf_fast(p0);
                    pf[cs][4 + r] = (short)f2bf_fast(p1);
                }
            }

            // PV: A = own-lane P fragments, B = V^T via two b64 reads per fragment
            __builtin_amdgcn_s_setprio(1);
#pragma unroll
            for (int cs = 0; cs < 4; ++cs) {
#pragma unroll
                for (int dt = 0; dt < 4; ++dt) {
                    const int d = dt * 16 + nl;
                    const int base = d * 128 + ((lq & 1) << 2);
                    const int cA = (((cs << 2) + (lq >> 1)) ^ nl) << 3;
                    const int cB = (((cs << 2) + 2 + (lq >> 1)) ^ nl) << 3;
                    sfrag4 va = *(const sfrag4*)&VT[base + cA];
                    sfrag4 vb = *(const sfrag4*)&VT[base + cB];
                    bfrag vf = __builtin_shufflevector(va, vb, 0, 1, 2, 3, 4, 5, 6, 7);
                    Oa[dt] = __builtin_amdgcn_mfma_f32_16x16x32_bf16(pf[cs], vf, Oa[dt], 0, 0, 0);
                }
            }
            __builtin_amdgcn_s_setprio(0);
        }

        // epilogue: reduce li across the 4 lq groups, transpose-broadcast, store
        li += __shfl_xor(li, 16, 64);
        li += __shfl_xor(li, 32, 64);
#pragma unroll
        for (int r = 0; r < 4; ++r) {
            const float lr = __shfl(li, lq * 4 + r, 64);
            const float inv = 1.f / lr;
            const int row = rowb + lq * 4 + r;
#pragma unroll
            for (int dt = 0; dt < 4; ++dt)
                yb[(size_t)row * En + dt * 16 + nl] = f2bf(Oa[dt][r] * inv);
        }
    }
}

extern "C" void kernel_launch(void* const* d_in, const int* in_sizes, int n_in,
                              void* d_out, int out_size, void* d_ws, size_t ws_size,
                              hipStream_t stream)
{
    const float* x      = (const float*)d_in[0];
    const float* W_qkv  = (const float*)d_in[1];
    const float* b_qkv  = (const float*)d_in[2];
    const float* W_proj = (const float*)d_in[3];
    const float* b_proj = (const float*)d_in[4];
    float* out = (float*)d_out;

    const int M = Bn * Tn;   // 8192
    char* ws = (char*)d_ws;
    unsigned short* xb   = (unsigned short*)ws; ws += (size_t)M * En * 2;
    unsigned short* Wqt  = (unsigned short*)ws; ws += (size_t)3 * En * En * 2;
    unsigned short* Wpt  = (unsigned short*)ws; ws += (size_t)En * En * 2;
    unsigned short* qkb  = (unsigned short*)ws; ws += (size_t)M * 2 * En * 2;   // Q|K
    unsigned short* vtg  = (unsigned short*)ws; ws += (size_t)M * En * 2;       // V^T per head
    unsigned short* yb   = (unsigned short*)ws;

    f2bf_vec<<<(M * En / 4 + 255) / 256, 256, 0, stream>>>(x, xb, M * En);
    transpose_f2bf<<<dim3(3 * En / 64, En / 64), 256, 0, stream>>>(W_qkv, Wqt, En, 3 * En);
    transpose_f2bf<<<dim3(En / 64, En / 64), 256, 0, stream>>>(W_proj, Wpt, En, En);

    // QKV: 256^2 8-wave 4-phase counted-vmcnt GEMM (384 blocks, 2 rounds)
    gemm_qkv_256<<<dim3(384), 512, 0, stream>>>(xb, Wqt, b_qkv, qkb, vtg);

    attn_mfma<<<dim3(1024), 256, 0, stream>>>(qkb, vtg, yb);

    gemm_nt_mfma<0, 0><<<dim3((En / 128) * (M / 128)), 256, 0, stream>>>(
        yb, Wpt, b_proj, out, En, nullptr, 1 << 30, M, En, En, 0, En / 128);
}

// Round 5
// 247.781 us; speedup vs baseline: 1.0428x; 1.0428x over previous
//
#include <hip/hip_runtime.h>
#include <math.h>

#define Bn 4
#define Tn 2048
#define En 1024
#define Hn 16
#define Dn 64
#define RS2 (2 * En)
#define QSCALE 0.18033688f   // (1/sqrt(64)) * log2(e)  -> softmax in exp2 domain
#define SMAX 16.0f           // static softmax max (log2 domain); scores bounded << 16

typedef __attribute__((ext_vector_type(8))) short bfrag;   // 8 bf16 in 4 VGPRs
typedef __attribute__((ext_vector_type(4))) short sfrag4;  // 4 bf16 in 2 VGPRs
typedef __attribute__((ext_vector_type(4))) float ffrag;   // 4 fp32 acc

__device__ __forceinline__ unsigned short f2bf(float f) {
    union { float f; unsigned int u; } v; v.f = f;
    unsigned int r = v.u + 0x7fffu + ((v.u >> 16) & 1u);   // RNE
    return (unsigned short)(r >> 16);
}
__device__ __forceinline__ unsigned short f2bf_fast(float f) {  // positive, no NaN
    union { float f; unsigned int u; } v; v.f = f;
    return (unsigned short)((v.u + 0x8000u) >> 16);
}

__device__ __forceinline__ void glds16(const unsigned short* g, unsigned short* l) {
    __builtin_amdgcn_global_load_lds(
        (const __attribute__((address_space(1))) unsigned int*)g,
        (__attribute__((address_space(3))) unsigned int*)l, 16, 0, 0);
}

#define VMCNT0() asm volatile("s_waitcnt vmcnt(0)" ::: "memory")
#define BAR()    __builtin_amdgcn_s_barrier()

// ---------------- fp32 -> bf16 elementwise ----------------
__global__ __launch_bounds__(256) void f2bf_vec(const float* __restrict__ in,
                                                unsigned short* __restrict__ out, int n) {
    int i = (blockIdx.x * 256 + threadIdx.x) * 4;
    if (i >= n) return;
    float4 v = *(const float4*)(in + i);
    ushort4 o;
    o.x = f2bf(v.x); o.y = f2bf(v.y); o.z = f2bf(v.z); o.w = f2bf(v.w);
    *(ushort4*)(out + i) = o;
}

// ---------------- W[K][N] fp32 -> Wt[N][K] bf16 ----------------
__global__ __launch_bounds__(256) void transpose_f2bf(const float* __restrict__ W,
                                                      unsigned short* __restrict__ Wt,
                                                      int K, int N) {
    __shared__ float s[64][65];
    const int kt = blockIdx.y * 64, nt = blockIdx.x * 64;
    const int tx = threadIdx.x & 15, ty = threadIdx.x >> 4;
#pragma unroll
    for (int i = 0; i < 4; ++i) {
        float4 v = *(const float4*)&W[(size_t)(kt + ty + i * 16) * N + nt + tx * 4];
        s[ty + i * 16][tx * 4 + 0] = v.x;
        s[ty + i * 16][tx * 4 + 1] = v.y;
        s[ty + i * 16][tx * 4 + 2] = v.z;
        s[ty + i * 16][tx * 4 + 3] = v.w;
    }
    __syncthreads();
#pragma unroll
    for (int i = 0; i < 4; ++i) {
        const int n = ty + i * 16;
        ushort4 o;
        o.x = f2bf(s[tx * 4 + 0][n]);
        o.y = f2bf(s[tx * 4 + 1][n]);
        o.z = f2bf(s[tx * 4 + 2][n]);
        o.w = f2bf(s[tx * 4 + 3][n]);
        *(ushort4*)&Wt[(size_t)(nt + n) * K + kt + tx * 4] = o;
    }
}

// ---------------- NT bf16 MFMA GEMM, 128x128, BK=64, single-barrier dbuf ----------------
// C = A[M,K] @ Bt[N,K]^T + bias. 128x128 tile, 4 waves (2x2 of 64x64), chunk-XOR LDS
// swizzle (0 bank conflicts, measured). T3-minimal pipeline: per K-tile
//   { issue STAGE(tile it+1 -> buf^1) ; ds_read+MFMA from buf (compiler-scheduled,
//     NO asm lgkm pinning) ; vmcnt(0) ; s_barrier }
// One barrier per K-tile (was 2); staging HBM latency hides under the ~640-cyc MFMA
// cluster instead of being serially drained between two barriers. LDS 64KB -> 2 blocks/CU
// co-resident (cross-block overlap preserved). Accumulation order identical to the
// 2-barrier version -> bitwise-same numerics.
template <int OUT_BF16, int VSPLIT>
__global__ __launch_bounds__(256) void gemm_nt_mfma(
    const unsigned short* __restrict__ A, const unsigned short* __restrict__ Bt,
    const float* __restrict__ bias, void* __restrict__ Cv, int ldc,
    unsigned short* __restrict__ vt, int vstart,
    int M, int N, int K, int qcols, int gx)
{
    __shared__ __attribute__((aligned(16))) unsigned short As[2][128 * 64];
    __shared__ __attribute__((aligned(16))) unsigned short Bs[2][128 * 64];

    const int t = threadIdx.x;
    const int w = t >> 6, l = t & 63;
    const int wmt = (w & 1) * 4, wnt = (w >> 1) * 4;
    const int nl = l & 15, lq = l >> 4;
    const int r8 = l >> 3, c8 = l & 7;        // staging: row-in-group / chunk
    const int cs8 = c8 ^ r8;                  // swizzled source chunk

    // XCD-aware flat -> tile mapping (xcd = flat % 8 heuristic)
    const int flat = blockIdx.x;
    const int xcd = flat & 7;
    const int g = flat >> 3;
    const int bx = g % gx;
    const int by = xcd * 8 + g / gx;          // M/128 == 64 -> 8 slabs per XCD
    const int m0 = by * 128, n0 = bx * 128;

    ffrag acc[4][4];
#pragma unroll
    for (int i = 0; i < 4; ++i)
#pragma unroll
        for (int j = 0; j < 4; ++j)
#pragma unroll
            for (int r = 0; r < 4; ++r) acc[i][j][r] = 0.f;

    const unsigned short* Ag = A  + (size_t)(m0 + r8) * K + cs8 * 8;
    const unsigned short* Bg = Bt + (size_t)(n0 + r8) * K + cs8 * 8;

    const int iters = K >> 6;   // 16

    // prologue: stage tile 0 into buf 0; full drain before first compute
#pragma unroll
    for (int r = 0; r < 4; ++r) {
        const int i = w * 4 + r;
        glds16(Ag + (size_t)(i * 8) * K, &As[0][i * 512 + l * 8]);
        glds16(Bg + (size_t)(i * 8) * K, &Bs[0][i * 512 + l * 8]);
    }
    __syncthreads();

#pragma unroll 1
    for (int it = 0; it < iters; ++it) {
        const int cur = it & 1;
        if (it + 1 < iters) {
            const int kn = (it + 1) << 6;
#pragma unroll
            for (int r = 0; r < 4; ++r) {
                const int i = w * 4 + r;
                glds16(Ag + (size_t)(i * 8) * K + kn, &As[cur ^ 1][i * 512 + l * 8]);
                glds16(Bg + (size_t)(i * 8) * K + kn, &Bs[cur ^ 1][i * 512 + l * 8]);
            }
        }
#pragma unroll
        for (int ks = 0; ks < 2; ++ks) {
            bfrag af[4], bf[4];
#pragma unroll
            for (int i = 0; i < 4; ++i) {
                const int pos = ((ks * 4 + lq) ^ (nl & 7)) << 3;
                af[i] = *(const bfrag*)&As[cur][((wmt + i) * 16 + nl) * 64 + pos];
                bf[i] = *(const bfrag*)&Bs[cur][((wnt + i) * 16 + nl) * 64 + pos];
            }
#pragma unroll
            for (int i = 0; i < 4; ++i)
#pragma unroll
                for (int j = 0; j < 4; ++j)
                    acc[i][j] = __builtin_amdgcn_mfma_f32_16x16x32_bf16(af[i], bf[j], acc[i][j], 0, 0, 0);
        }
        VMCNT0();   // own staging of buf^1 landed (cheap: hidden under MFMA cluster)
        BAR();      // all waves done reading buf + staged buf^1 -> safe to swap
    }

    const int orow = lq * 4, ocol = nl;
#pragma unroll
    for (int i = 0; i < 4; ++i) {
        const int gm = m0 + (wmt + i) * 16 + orow;
#pragma unroll
        for (int j = 0; j < 4; ++j) {
            const int gn = n0 + (wnt + j) * 16 + ocol;
            const float bs = bias[gn];
            if (VSPLIT && gn >= vstart) {
                const int vc = gn - vstart;
                const int b  = gm / Tn;
                const int tt = gm - b * Tn;
                ushort4 o;
                o.x = f2bf(acc[i][j][0] + bs);
                o.y = f2bf(acc[i][j][1] + bs);
                o.z = f2bf(acc[i][j][2] + bs);
                o.w = f2bf(acc[i][j][3] + bs);
                *(ushort4*)&vt[(size_t)(b * Hn * Dn + vc) * Tn + tt] = o;
            } else {
                const float sc = (qcols && gn < qcols) ? QSCALE : 1.f;
#pragma unroll
                for (int r = 0; r < 4; ++r) {
                    const float vv = (acc[i][j][r] + bs) * sc;
                    if (OUT_BF16)
                        ((unsigned short*)Cv)[(size_t)(gm + r) * ldc + gn] = f2bf(vv);
                    else
                        ((float*)Cv)[(size_t)(gm + r) * ldc + gn] = vv;
                }
            }
        }
    }
}

// ---------------- MFMA flash attention, swapped-QK^T in-register softmax ----------------
__global__ __launch_bounds__(256, 4) void attn_mfma(
    const unsigned short* __restrict__ qkv,   // [B*T][2E]  Q|K, Q pre-scaled
    const unsigned short* __restrict__ vtg,   // [B*H*D][T] V transposed
    unsigned short* __restrict__ yattn)       // [B*T][E]
{
    __shared__ __attribute__((aligned(16))) unsigned short KT[128 * 64];
    __shared__ __attribute__((aligned(16))) unsigned short VT[64 * 128];

    const int t = threadIdx.x;
    const int w = t >> 6, l = t & 63;
    const int nl = l & 15, lq = l >> 4;
    const int flat = blockIdx.x;
    const int bh = flat & 63;
    const int qp = flat >> 6;         // 0..15
    const int b = bh >> 4, h = bh & 15;

    const unsigned short* qbase = qkv + (size_t)(b * Tn) * RS2 + h * Dn;
    const unsigned short* kbase = qbase + En;
    const unsigned short* vbase = vtg + (size_t)(bh * Dn) * Tn;
    unsigned short* yb = yattn + (size_t)(b * Tn) * En + h * Dn;

#pragma unroll 1
    for (int phase = 0; phase < 2; ++phase) {
        const int qt = phase ? (31 - qp) : qp;
        const int rowb = qt * 64 + w * 16;
        const int jmax = qt >> 1;
        const int qrow = rowb + nl;

        bfrag qf[2];
#pragma unroll
        for (int ks = 0; ks < 2; ++ks)
            qf[ks] = *(const bfrag*)(qbase + (size_t)(rowb + nl) * RS2 + ks * 32 + lq * 8);

        ffrag Oa[4];
        float li = 0.f;
#pragma unroll
        for (int dt = 0; dt < 4; ++dt)
#pragma unroll
            for (int r = 0; r < 4; ++r) Oa[dt][r] = 0.f;

        for (int j = 0; j <= jmax; ++j) {
            const int k0 = j << 7;
            __syncthreads();   // prior tile's frag reads done before restage
#pragma unroll
            for (int r = 0; r < 4; ++r) {
                const int i = w * 4 + r;
                glds16(kbase + (size_t)(k0 + i * 8 + (l >> 3)) * RS2 + (((l & 7) ^ (l >> 3)) << 3),
                       &KT[i * 512 + l * 8]);
            }
#pragma unroll
            for (int r = 0; r < 4; ++r) {
                const int i = w * 4 + r;
                const int key = ((i & 3) << 2) + (l >> 4);
                glds16(vbase + (size_t)(i * 4 + (l >> 4)) * Tn + k0 + (((l & 15) ^ key) << 3),
                       &VT[i * 512 + l * 8]);
            }
            __syncthreads();

            // QK^T swapped + softmax fully in-register
            bfrag pf[4];
#pragma unroll
            for (int cs = 0; cs < 4; ++cs) {
                const int n0 = cs * 2, n1 = cs * 2 + 1;
                const int pos0 = (lq ^ (nl & 7)) << 3;
                const int pos1 = ((4 + lq) ^ (nl & 7)) << 3;
                bfrag ka0 = *(const bfrag*)&KT[(n0 * 16 + nl) * 64 + pos0];
                bfrag kb0 = *(const bfrag*)&KT[(n0 * 16 + nl) * 64 + pos1];
                bfrag ka1 = *(const bfrag*)&KT[(n1 * 16 + nl) * 64 + pos0];
                bfrag kb1 = *(const bfrag*)&KT[(n1 * 16 + nl) * 64 + pos1];
                ffrag z0, z1;
#pragma unroll
                for (int r = 0; r < 4; ++r) { z0[r] = -SMAX; z1[r] = -SMAX; }
                __builtin_amdgcn_s_setprio(1);
                z0 = __builtin_amdgcn_mfma_f32_16x16x32_bf16(ka0, qf[0], z0, 0, 0, 0);
                z0 = __builtin_amdgcn_mfma_f32_16x16x32_bf16(kb0, qf[1], z0, 0, 0, 0);
                z1 = __builtin_amdgcn_mfma_f32_16x16x32_bf16(ka1, qf[0], z1, 0, 0, 0);
                z1 = __builtin_amdgcn_mfma_f32_16x16x32_bf16(kb1, qf[1], z1, 0, 0, 0);
                __builtin_amdgcn_s_setprio(0);
                if (j == jmax) {   // tile containing the diagonal: causal mask
#pragma unroll
                    for (int r = 0; r < 4; ++r) {
                        if (k0 + n0 * 16 + lq * 4 + r > qrow) z0[r] = -INFINITY;
                        if (k0 + n1 * 16 + lq * 4 + r > qrow) z1[r] = -INFINITY;
                    }
                }
#pragma unroll
                for (int r = 0; r < 4; ++r) {
                    const float p0 = __builtin_amdgcn_exp2f(z0[r]);
                    const float p1 = __builtin_amdgcn_exp2f(z1[r]);
                    li += p0;
                    li += p1;
                    pf[cs][r]     = (short)f2bf_fast(p0);
                    pf[cs][4 + r] = (short)f2bf_fast(p1);
                }
            }

            // PV: A = own-lane P fragments, B = V^T via two b64 reads per fragment
            __builtin_amdgcn_s_setprio(1);
#pragma unroll
            for (int cs = 0; cs < 4; ++cs) {
#pragma unroll
                for (int dt = 0; dt < 4; ++dt) {
                    const int d = dt * 16 + nl;
                    const int base = d * 128 + ((lq & 1) << 2);
                    const int cA = (((cs << 2) + (lq >> 1)) ^ nl) << 3;
                    const int cB = (((cs << 2) + 2 + (lq >> 1)) ^ nl) << 3;
                    sfrag4 va = *(const sfrag4*)&VT[base + cA];
                    sfrag4 vb = *(const sfrag4*)&VT[base + cB];
                    bfrag vf = __builtin_shufflevector(va, vb, 0, 1, 2, 3, 4, 5, 6, 7);
                    Oa[dt] = __builtin_amdgcn_mfma_f32_16x16x32_bf16(pf[cs], vf, Oa[dt], 0, 0, 0);
                }
            }
            __builtin_amdgcn_s_setprio(0);
        }

        // epilogue: reduce li across the 4 lq groups, transpose-broadcast, store
        li += __shfl_xor(li, 16, 64);
        li += __shfl_xor(li, 32, 64);
#pragma unroll
        for (int r = 0; r < 4; ++r) {
            const float lr = __shfl(li, lq * 4 + r, 64);
            const float inv = 1.f / lr;
            const int row = rowb + lq * 4 + r;
#pragma unroll
            for (int dt = 0; dt < 4; ++dt)
                yb[(size_t)row * En + dt * 16 + nl] = f2bf(Oa[dt][r] * inv);
        }
    }
}

extern "C" void kernel_launch(void* const* d_in, const int* in_sizes, int n_in,
                              void* d_out, int out_size, void* d_ws, size_t ws_size,
                              hipStream_t stream)
{
    const float* x      = (const float*)d_in[0];
    const float* W_qkv  = (const float*)d_in[1];
    const float* b_qkv  = (const float*)d_in[2];
    const float* W_proj = (const float*)d_in[3];
    const float* b_proj = (const float*)d_in[4];
    float* out = (float*)d_out;

    const int M = Bn * Tn;   // 8192
    char* ws = (char*)d_ws;
    unsigned short* xb   = (unsigned short*)ws; ws += (size_t)M * En * 2;
    unsigned short* Wqt  = (unsigned short*)ws; ws += (size_t)3 * En * En * 2;
    unsigned short* Wpt  = (unsigned short*)ws; ws += (size_t)En * En * 2;
    unsigned short* qkb  = (unsigned short*)ws; ws += (size_t)M * 2 * En * 2;   // Q|K
    unsigned short* vtg  = (unsigned short*)ws; ws += (size_t)M * En * 2;       // V^T per head
    unsigned short* yb   = (unsigned short*)ws;

    f2bf_vec<<<(M * En / 4 + 255) / 256, 256, 0, stream>>>(x, xb, M * En);
    transpose_f2bf<<<dim3(3 * En / 64, En / 64), 256, 0, stream>>>(W_qkv, Wqt, En, 3 * En);
    transpose_f2bf<<<dim3(En / 64, En / 64), 256, 0, stream>>>(W_proj, Wpt, En, En);

    gemm_nt_mfma<1, 1><<<dim3((3 * En / 128) * (M / 128)), 256, 0, stream>>>(
        xb, Wqt, b_qkv, qkb, 2 * En, vtg, 2 * En, M, 3 * En, En, En, 3 * En / 128);

    attn_mfma<<<dim3(1024), 256, 0, stream>>>(qkb, vtg, yb);

    gemm_nt_mfma<0, 0><<<dim3((En / 128) * (M / 128)), 256, 0, stream>>>(
        yb, Wpt, b_proj, out, En, nullptr, 1 << 30, M, En, En, 0, En / 128);
}